// Round 2
// baseline (1525.170 us; speedup 1.0000x reference)
//
#include <hip/hip_runtime.h>
#include <stdint.h>

#define T_LEN 1024
#define H 256
#define B_SZ 128

typedef __attribute__((ext_vector_type(8))) __bf16 bf16x8;
typedef __attribute__((ext_vector_type(4))) float f32x4;
typedef __attribute__((ext_vector_type(2))) float f32x2;

__device__ __forceinline__ unsigned short f32_to_bf16_rne(float f) {
  union { float f; unsigned int u; } c{f};
  unsigned int r = 0x7FFFu + ((c.u >> 16) & 1u);
  c.u += r;
  return (unsigned short)(c.u >> 16);
}
__device__ __forceinline__ float bf16_to_f32(unsigned short h) {
  union { unsigned int u; float f; } c{(unsigned int)h << 16};
  return c.f;
}

// DPP quad-perm add: x + x[lane ^ 1] (CTRL=0xB1) or x + x[lane ^ 2] (CTRL=0x4E)
template <int CTRL>
__device__ __forceinline__ float dpp_xor_add(float x) {
  int v = __builtin_amdgcn_update_dpp(0, __float_as_int(x), CTRL, 0xF, 0xF, true);
  return x + __int_as_float(v);
}

// x + x[lane ^ 32] without touching the LDS pipe.
__device__ __forceinline__ float xor32_add(float x) {
#if __has_builtin(__builtin_amdgcn_permlane32_swap)
  const int xi = __float_as_int(x);
  auto r = __builtin_amdgcn_permlane32_swap(xi, xi, false, false);
  return __int_as_float((int)r[0]) + __int_as_float((int)r[1]);
#else
  return x + __shfl_xor(x, 32, 64);
#endif
}

// ---------------------------------------------------------------- h0 kernel
__global__ void h0_kernel(const float* __restrict__ W1, const float* __restrict__ b1,
                          const float* __restrict__ W2, const float* __restrict__ b2,
                          float* __restrict__ h0) {
  __shared__ float hid[64];
  const int tid = threadIdx.x;
  if (tid < 64) hid[tid] = fmaxf(W1[tid * 2 + 0] + W1[tid * 2 + 1] + b1[tid], 0.0f);
  __syncthreads();
  float acc = b2[tid];
  #pragma unroll
  for (int j = 0; j < 64; ++j) acc = fmaf(W2[tid * 64 + j], hid[j], acc);
  h0[tid] = fmaxf(acc, 0.0f);
}

// ---------------------------------------------------------------- recurrence
// One block per batch, 512 threads (8 waves, 2/SIMD).
// Lane owns 4 outputs (o = w*32 + g + 8s) over one 32-wide k-eighth.
// Weights held as 64 f32x2 (128 VGPR) and LAUNDERED through empty asm so the
// per-step "memory"-clobber barrier cannot force reloads (round-1: VGPR=80
// proved the loads sank into the loop -> L2-BW-bound on W_hh re-reads).
// Inner product uses v_pk_fma_f32 (float2 elementwise fma): 64 pk-FMA/step
// instead of 128 scalar FMA. k-pairs come free from the float4 LDS read.
__global__ __launch_bounds__(512, 2) void rnn_kernel(
    const float* __restrict__ inputs, const float* __restrict__ W_ih,
    const float* __restrict__ W_hh, const float* __restrict__ h0,
    float* __restrict__ p_out) {
  __shared__ float hbuf[2][H];
  const int b = blockIdx.x;
  const int tid = threadIdx.x;
  const int lane = tid & 63;
  const int w = tid >> 6;           // wave 0..7 -> output block [w*32, w*32+32)
  const int qlow = lane & 3;
  const int q2 = lane >> 5;         // 0..1
  const int q = qlow | (q2 << 2);   // k-eighth 0..7 -> k in [q*32, q*32+32)
  const int g = (lane >> 2) & 7;    // 0..7

  // ---- weights: rows o_s = w*32 + g + 8s, cols [q*32, q*32+32) as f32x2 ----
  f32x2 w0[16], w1[16], w2[16], w3[16];
  {
    const float* Wq = W_hh + (size_t)q * 32;
    const f32x2* r0 = reinterpret_cast<const f32x2*>(Wq + (size_t)(w * 32 + g +  0) * H);
    const f32x2* r1 = reinterpret_cast<const f32x2*>(Wq + (size_t)(w * 32 + g +  8) * H);
    const f32x2* r2 = reinterpret_cast<const f32x2*>(Wq + (size_t)(w * 32 + g + 16) * H);
    const f32x2* r3 = reinterpret_cast<const f32x2*>(Wq + (size_t)(w * 32 + g + 24) * H);
    #pragma unroll
    for (int jj = 0; jj < 16; ++jj) {
      w0[jj] = r0[jj]; w1[jj] = r1[jj]; w2[jj] = r2[jj]; w3[jj] = r3[jj];
    }
  }
  // launder: make weights opaque SSA values -> cannot be rematerialized from
  // memory across the "memory"-clobber step barrier.
  #pragma unroll
  for (int jj = 0; jj < 16; ++jj) {
    asm volatile("" : "+v"(w0[jj]));
    asm volatile("" : "+v"(w1[jj]));
    asm volatile("" : "+v"(w2[jj]));
    asm volatile("" : "+v"(w3[jj]));
  }

  // swizzled float4 read indices for this lane's k-eighth
  int hidx[8];
  #pragma unroll
  for (int j = 0; j < 8; ++j) hidx[j] = (q << 3) | (j ^ q);

  // duty output this lane finalizes (q2=0 -> LDS h write, q2=1 -> global p)
  const int duty = w * 32 + g + 8 * qlow;
  const int jd = (duty >> 2) & 7;
  const int dIdx = (w << 5) | ((jd ^ w) << 2) | (duty & 3);  // swizzled slot
  float wih0 = W_ih[duty * 3 + 0];
  float wih1 = W_ih[duty * 3 + 1];
  float wih2 = W_ih[duty * 3 + 2];
  asm volatile("" : "+v"(wih0), "+v"(wih1), "+v"(wih2));

  // init h (swizzled store of h0)
  if (tid < H) {
    const int o = tid;
    const int jo = (o >> 2) & 7;
    const int qo = o >> 5;
    hbuf[0][(qo << 5) | ((jo ^ qo) << 2) | (o & 3)] = h0[o];
  }

  const float* xb = inputs + (size_t)b * T_LEN * 3;
  float* po = p_out + (size_t)b * T_LEN * H + duty;
  __syncthreads();

#define RNN_STEP(CUR, NXT, TT, X0, X1, X2)                                   \
  {                                                                          \
    const float4* h4 = reinterpret_cast<const float4*>(hbuf[CUR]);           \
    f32x2 acc[2][4];                                                         \
    _Pragma("unroll") for (int pp = 0; pp < 2; ++pp)                         \
      _Pragma("unroll") for (int oo = 0; oo < 4; ++oo)                       \
        acc[pp][oo] = (f32x2){0.f, 0.f};                                     \
    _Pragma("unroll") for (int j = 0; j < 8; ++j) {                          \
      const float4 hv = h4[hidx[j]];                                         \
      const f32x2 hlo = {hv.x, hv.y};                                        \
      const f32x2 hhi = {hv.z, hv.w};                                        \
      const int par = j & 1;                                                 \
      acc[par][0] = __builtin_elementwise_fma(w0[2 * j], hlo, acc[par][0]);  \
      acc[par][1] = __builtin_elementwise_fma(w1[2 * j], hlo, acc[par][1]);  \
      acc[par][2] = __builtin_elementwise_fma(w2[2 * j], hlo, acc[par][2]);  \
      acc[par][3] = __builtin_elementwise_fma(w3[2 * j], hlo, acc[par][3]);  \
      acc[par][0] = __builtin_elementwise_fma(w0[2 * j + 1], hhi, acc[par][0]); \
      acc[par][1] = __builtin_elementwise_fma(w1[2 * j + 1], hhi, acc[par][1]); \
      acc[par][2] = __builtin_elementwise_fma(w2[2 * j + 1], hhi, acc[par][2]); \
      acc[par][3] = __builtin_elementwise_fma(w3[2 * j + 1], hhi, acc[par][3]); \
    }                                                                        \
    const f32x2 s0 = acc[0][0] + acc[1][0];                                  \
    const f32x2 s1 = acc[0][1] + acc[1][1];                                  \
    const f32x2 s2 = acc[0][2] + acc[1][2];                                  \
    const f32x2 s3 = acc[0][3] + acc[1][3];                                  \
    float a0 = s0.x + s0.y;                                                  \
    float a1 = s1.x + s1.y;                                                  \
    float a2 = s2.x + s2.y;                                                  \
    float a3 = s3.x + s3.y;                                                  \
    a0 = dpp_xor_add<0xB1>(a0); a0 = dpp_xor_add<0x4E>(a0); a0 = xor32_add(a0); \
    a1 = dpp_xor_add<0xB1>(a1); a1 = dpp_xor_add<0x4E>(a1); a1 = xor32_add(a1); \
    a2 = dpp_xor_add<0xB1>(a2); a2 = dpp_xor_add<0x4E>(a2); a2 = xor32_add(a2); \
    a3 = dpp_xor_add<0xB1>(a3); a3 = dpp_xor_add<0x4E>(a3); a3 = xor32_add(a3); \
    const float tot = qlow == 0 ? a0 : qlow == 1 ? a1 : qlow == 2 ? a2 : a3; \
    float hn = fmaf((X2), wih2, fmaf((X1), wih1, fmaf((X0), wih0, tot)));    \
    hn = fmaxf(hn, 0.0f);                                                    \
    if (lane < 32) hbuf[NXT][dIdx] = hn;                                     \
    else           po[(size_t)(TT) * H] = hn;                                \
    asm volatile("s_waitcnt lgkmcnt(0)\n\ts_barrier" ::: "memory");          \
  }

  for (int t = 0; t < T_LEN; t += 2) {
    const float y0 = xb[t * 3 + 0];
    const float y1 = xb[t * 3 + 1];
    const float y2 = xb[t * 3 + 2];
    const float z0 = xb[t * 3 + 3];
    const float z1 = xb[t * 3 + 4];
    const float z2 = xb[t * 3 + 5];
    RNN_STEP(0, 1, t,     y0, y1, y2);
    RNN_STEP(1, 0, t + 1, z0, z1, z2);
  }
#undef RNN_STEP
}

// ---------------------------------------------------------------- cvt + sq
__global__ void cvt_kernel(const float* __restrict__ p, unsigned short* __restrict__ pb,
                           float* __restrict__ sq) {
  const int gw = blockIdx.x * 4 + (threadIdx.x >> 6);  // global (b,t) index
  const int lane = threadIdx.x & 63;
  const float4 v = reinterpret_cast<const float4*>(p + (size_t)gw * H)[lane];
  const unsigned short u0 = f32_to_bf16_rne(v.x);
  const unsigned short u1 = f32_to_bf16_rne(v.y);
  const unsigned short u2 = f32_to_bf16_rne(v.z);
  const unsigned short u3 = f32_to_bf16_rne(v.w);
  ushort4 st;
  st.x = u0; st.y = u1; st.z = u2; st.w = u3;
  reinterpret_cast<ushort4*>(pb + (size_t)gw * H)[lane] = st;
  const float r0 = bf16_to_f32(u0), r1 = bf16_to_f32(u1);
  const float r2 = bf16_to_f32(u2), r3 = bf16_to_f32(u3);
  float s = r0 * r0 + r1 * r1 + r2 * r2 + r3 * r3;
  #pragma unroll
  for (int off = 32; off > 0; off >>= 1) s += __shfl_down(s, off, 64);
  if (lane == 0) sq[gw] = s;
}

// ---------------------------------------------------------------- gram + exp
// corr is SYMMETRIC per batch: compute only the 36 upper-triangle 128x128
// tiles (vs 64) and store each tile twice. The mirror store is float4 (lane
// holds 4 consecutive rows, same col -> consecutive cols transposed).
// Staging register-prefetches the next kc tile under the MFMA phase.
__global__ __launch_bounds__(256) void gram_kernel(
    const unsigned short* __restrict__ pb, const float* __restrict__ sq,
    float* __restrict__ corr) {
  __shared__ unsigned short At[128 * 64];
  __shared__ unsigned short Bt[128 * 64];
  __shared__ float sqT[128];
  __shared__ float sqS[128];

  const int b = blockIdx.y;
  // triangular decode: blockIdx.x in [0,36) -> (ti,si), ti<=si
  int ti = 0, rem = blockIdx.x;
  while (rem >= 8 - ti) { rem -= 8 - ti; ++ti; }
  const int si = ti + rem;
  const int t0 = ti * 128;
  const int s0 = si * 128;
  const int tid = threadIdx.x;

  if (tid < 128) sqT[tid] = sq[b * T_LEN + t0 + tid];
  else           sqS[tid - 128] = sq[b * T_LEN + s0 + (tid - 128)];

  const int lane = tid & 63;
  const int wave = tid >> 6;
  const int wm = wave >> 1;    // 0..1 (t dim)
  const int wn = wave & 1;     // 0..1 (s dim)
  const int m16 = lane & 15;
  const int kg = lane >> 4;    // 0..3

  f32x4 acc[4][4];
  #pragma unroll
  for (int i = 0; i < 4; ++i)
    #pragma unroll
    for (int j = 0; j < 4; ++j) acc[i][j] = (f32x4){0.f, 0.f, 0.f, 0.f};

  const size_t baseT = ((size_t)b * T_LEN + t0) * H;
  const size_t baseS = ((size_t)b * T_LEN + s0) * H;

  uint4 ra[4], rb[4];
#define GRAM_LD(KC)                                                          \
  { _Pragma("unroll") for (int i = 0; i < 4; ++i) {                          \
      const int c = tid + 256 * i; const int r = c >> 3; const int k8 = c & 7; \
      ra[i] = *reinterpret_cast<const uint4*>(pb + baseT + (size_t)r * H + (KC) * 64 + k8 * 8); \
      rb[i] = *reinterpret_cast<const uint4*>(pb + baseS + (size_t)r * H + (KC) * 64 + k8 * 8); } }

  GRAM_LD(0);
  #pragma unroll
  for (int kc = 0; kc < 4; ++kc) {
    #pragma unroll
    for (int i = 0; i < 4; ++i) {
      const int c = tid + 256 * i;
      const int r = c >> 3;
      const int k8 = c & 7;
      *reinterpret_cast<uint4*>(&At[r * 64 + k8 * 8]) = ra[i];
      *reinterpret_cast<uint4*>(&Bt[r * 64 + k8 * 8]) = rb[i];
    }
    __syncthreads();
    if (kc < 3) GRAM_LD(kc + 1);   // next-tile loads fly under the MFMAs

    #pragma unroll
    for (int k32 = 0; k32 < 64; k32 += 32) {
      bf16x8 af[4], bfm[4];
      #pragma unroll
      for (int i = 0; i < 4; ++i)
        af[i] = *reinterpret_cast<const bf16x8*>(
            &At[(wm * 64 + i * 16 + m16) * 64 + k32 + kg * 8]);
      #pragma unroll
      for (int j = 0; j < 4; ++j)
        bfm[j] = *reinterpret_cast<const bf16x8*>(
            &Bt[(wn * 64 + j * 16 + m16) * 64 + k32 + kg * 8]);
      #pragma unroll
      for (int i = 0; i < 4; ++i)
        #pragma unroll
        for (int j = 0; j < 4; ++j)
          acc[i][j] = __builtin_amdgcn_mfma_f32_16x16x32_bf16(af[i], bfm[j], acc[i][j], 0, 0, 0);
    }
    __syncthreads();
  }
#undef GRAM_LD

  // epilogue: dp = max(sq_t + sq_s - 2G, 0); corr = exp(-dp)
  // direct store: scattered dword into [t0.., s0..]
  // mirror store: float4 into [s0.., t0..] (4 consecutive cols per lane)
  #pragma unroll
  for (int i = 0; i < 4; ++i) {
    #pragma unroll
    for (int j = 0; j < 4; ++j) {
      const int trow0 = wm * 64 + i * 16 + kg * 4;
      const int scol = wn * 64 + j * 16 + m16;
      float ev[4];
      #pragma unroll
      for (int r = 0; r < 4; ++r) {
        const float dp = fmaxf(sqT[trow0 + r] + sqS[scol] - 2.0f * acc[i][j][r], 0.0f);
        ev[r] = __expf(-dp);
        corr[((size_t)b * T_LEN + t0 + trow0 + r) * T_LEN + s0 + scol] = ev[r];
      }
      float4 mv;
      mv.x = ev[0]; mv.y = ev[1]; mv.z = ev[2]; mv.w = ev[3];
      *reinterpret_cast<float4*>(
          &corr[((size_t)b * T_LEN + s0 + scol) * T_LEN + t0 + trow0]) = mv;
    }
  }
}

// ---------------------------------------------------------------- launch
extern "C" void kernel_launch(void* const* d_in, const int* in_sizes, int n_in,
                              void* d_out, int out_size, void* d_ws, size_t ws_size,
                              hipStream_t stream) {
  const float* inputs = (const float*)d_in[0];
  const float* W1   = (const float*)d_in[1];
  const float* b1   = (const float*)d_in[2];
  const float* W2   = (const float*)d_in[3];
  const float* b2   = (const float*)d_in[4];
  const float* W_ih = (const float*)d_in[5];
  const float* W_hh = (const float*)d_in[6];

  float* corr = (float*)d_out;                              // [B,T,T]
  float* p = corr + (size_t)B_SZ * T_LEN * T_LEN;           // [B,T,H]

  unsigned short* pb = (unsigned short*)d_ws;               // [B,T,H] bf16 (64 MB)
  float* sq = (float*)((char*)d_ws + (size_t)B_SZ * T_LEN * H * 2);  // [B,T]
  float* h0 = sq + (size_t)B_SZ * T_LEN;                    // [H]

  h0_kernel<<<1, 256, 0, stream>>>(W1, b1, W2, b2, h0);
  rnn_kernel<<<B_SZ, 512, 0, stream>>>(inputs, W_ih, W_hh, h0, p);
  cvt_kernel<<<B_SZ * T_LEN / 4, 256, 0, stream>>>(p, pb, sq);
  gram_kernel<<<dim3(36, B_SZ), 256, 0, stream>>>(pb, sq, corr);
}